// Round 2
// baseline (275.349 us; speedup 1.0000x reference)
//
#include <hip/hip_runtime.h>
#include <math.h>

#define D2R   0.017453292519943295f
#define TWO_R 7917.6f   /* 2 * 3958.8 miles */
#define TAU   0.25f
#define INV_TAU 4.0f
#define BIG   3.0e38f

// ---------------- kernel 1: per-candidate trig precompute ----------------
// bin_coords is (NBINS*M, 2) flat: [lon, lat] in degrees.
// Store float4 {lat_rad, lon_rad, cos(lat_rad), 0}.
__global__ __launch_bounds__(256) void prep_cand(
    const float* __restrict__ bc, float4* __restrict__ ct, int total) {
  int i = blockIdx.x * 256 + threadIdx.x;
  if (i < total) {
    float lon  = bc[2 * i + 0];
    float lat  = bc[2 * i + 1];
    float latr = lat * D2R;
    float lonr = lon * D2R;
    ct[i] = make_float4(latr, lonr, cosf(latr), 0.0f);
  }
}

// ---------------- kernel 2: per-pred softmin via logsumexp ----------------
// One block (256 threads) per prediction. Each thread owns ITERS candidates,
// keeps distances in registers (static unroll -> no scratch), block-reduces
// the min, then one v_exp per candidate.
template <int ITERS>
__global__ __launch_bounds__(256) void lse_kernel(
    const float*  __restrict__ preds,
    const float4* __restrict__ ct,
    const int*    __restrict__ xv,
    const int*    __restrict__ bin_counts,
    float* __restrict__ accF, int* __restrict__ accI, int M) {
  const int b   = blockIdx.x;
  const int tid = threadIdx.x;

  const int bin = xv[3 * b] * 25 + xv[3 * b + 1] * 5 + xv[3 * b + 2];
  const int cnt = bin_counts[bin];

  const float lon1 = preds[2 * b + 0] * D2R;
  const float lat1 = preds[2 * b + 1] * D2R;
  const float cl1  = __cosf(lat1);

  const float4* __restrict__ cb = ct + (size_t)bin * (size_t)M;

  float dd[ITERS];
  float dmin = BIG;
#pragma unroll
  for (int r = 0; r < ITERS; ++r) {
    const int m = tid + r * 256;
    float dist  = BIG;
    if (m < cnt) {
      float4 c = cb[m];
      // haversine with precomputed cos(lat2): args to sin are < 0.5 rad,
      // so __sinf (v_sin) needs no range reduction.
      float sd = __sinf(0.5f * (c.x - lat1));
      float sn = __sinf(0.5f * (c.y - lon1));
      float a  = fmaf(sd, sd, cl1 * c.z * (sn * sn));
      a = fminf(fmaxf(a, 0.0f), 1.0f);
      dist = TWO_R * asinf(sqrtf(a));   // == R * 2*atan2(sqrt(a), sqrt(1-a))
    }
    dd[r] = dist;
    dmin  = fminf(dmin, dist);
  }

  // ---- block-wide min(dmin) ----
  __shared__ float redm[4];
  __shared__ float reds[4];
#pragma unroll
  for (int o = 32; o; o >>= 1) dmin = fminf(dmin, __shfl_xor(dmin, o));
  const int wave = tid >> 6;
  if ((tid & 63) == 0) redm[wave] = dmin;
  __syncthreads();
  dmin = fminf(fminf(redm[0], redm[1]), fminf(redm[2], redm[3]));

  // ---- sum of exp((dmin - d)/tau): masked slots have d=BIG -> exp -> 0 ----
  float s = 0.0f;
#pragma unroll
  for (int r = 0; r < ITERS; ++r)
    s += __expf((dmin - dd[r]) * INV_TAU);

#pragma unroll
  for (int o = 32; o; o >>= 1) s += __shfl_xor(s, o);
  if ((tid & 63) == 0) reds[wave] = s;
  __syncthreads();   // REQUIRED: tid 0 reads all four waves' partials below

  if (tid == 0 && cnt > 0) {
    float S    = reds[0] + reds[1] + reds[2] + reds[3];
    float soft = dmin - TAU * logf(S);   // = -tau * logsumexp(-d/tau)
    atomicAdd(accF, soft);
    atomicAdd(accI, 1);
  }
}

// ---------------- kernel 3: finalize ----------------
__global__ void fin_kernel(const float* __restrict__ accF,
                           const int* __restrict__ accI,
                           float* __restrict__ out) {
  int nv = *accI;
  if (nv < 1) nv = 1;
  out[0] = accF[0] / (float)nv;
}

extern "C" void kernel_launch(void* const* d_in, const int* in_sizes, int n_in,
                              void* d_out, int out_size, void* d_ws, size_t ws_size,
                              hipStream_t stream) {
  const float* preds      = (const float*)d_in[0];   // (B,2) [lon,lat]
  const float* bin_coords = (const float*)d_in[1];   // (125,M,2) [lon,lat]
  const int*   x_vals     = (const int*)d_in[2];     // (B,3)
  const int*   bin_counts = (const int*)d_in[3];     // (125,)
  float*       out        = (float*)d_out;

  const int B     = in_sizes[0] / 2;
  const int total = in_sizes[1] / 2;                 // NBINS * M candidates
  const int NBINS = 125;
  const int M     = total / NBINS;                   // 4096

  // ws layout: [0] float sum, [4] int n_valid, [16..) float4 cand_trig
  float*  accF = (float*)d_ws;
  int*    accI = (int*)((char*)d_ws + 4);
  float4* ct   = (float4*)((char*)d_ws + 16);

  hipMemsetAsync(d_ws, 0, 16, stream);

  prep_cand<<<(total + 255) / 256, 256, 0, stream>>>(bin_coords, ct, total);

  // M = 4096 -> 16 candidates per thread
  lse_kernel<16><<<B, 256, 0, stream>>>(preds, ct, x_vals, bin_counts,
                                        accF, accI, M);

  fin_kernel<<<1, 1, 0, stream>>>(accF, accI, out);
}